// Round 3
// baseline (220.569 us; speedup 1.0000x reference)
//
#include <hip/hip_runtime.h>
#include <hip/hip_bf16.h>

#define BDIM 16384
#define CDIM 128
#define FDIM 5000
#define EDIM 20000
#define ELLW 16
#define MAXOVF 20000
#define NT4  10       // n-tile QUADS per bm: 40 n-tiles / 4
#define NGEMM 1280    // 128 bm x 10 quads
#define NSEG  2048    // BDIM/8 slabs
#define NBM   128
#define LAGB  52      // bm lag before interleaving seg tasks (>512 queue slots)

typedef __attribute__((ext_vector_type(8))) short short8;
typedef __attribute__((ext_vector_type(4))) float f32x4;
typedef __attribute__((ext_vector_type(2))) float f32x2;
typedef __attribute__((ext_vector_type(2))) int i32x2;
typedef __attribute__((ext_vector_type(8))) unsigned short upk8;
typedef __attribute__((ext_vector_type(4))) unsigned short upk4;
typedef __attribute__((ext_vector_type(2))) unsigned int u32x2;

__device__ __forceinline__ unsigned short f2bf(float f) {
    unsigned int u = __builtin_bit_cast(unsigned int, f);
    u = (u + 0x7fffu + ((u >> 16) & 1u)) >> 16;   // RNE
    return (unsigned short)u;
}
__device__ __forceinline__ float bf2f(unsigned short s) {
    unsigned int u = ((unsigned int)s) << 16;
    return __builtin_bit_cast(float, u);
}
// byte k of w -> bf16 of the integer value (EXACT for ints 0..255)
__device__ __forceinline__ unsigned short q2bf(unsigned int w, int k) {
    float f = (float)((w >> (8 * k)) & 0xFFu);    // v_cvt_f32_ubyteN
    return (unsigned short)(__builtin_bit_cast(unsigned int, f) >> 16);
}
__device__ __forceinline__ upk8 umax8(upk8 a, upk8 b) {
#if __has_builtin(__builtin_elementwise_max)
    return __builtin_elementwise_max(a, b);   // 4x v_pk_max_u16
#else
    upk8 r;
    #pragma unroll
    for (int j = 0; j < 8; ++j) r[j] = a[j] > b[j] ? a[j] : b[j];
    return r;
#endif
}
// single v_rcp_f32 (no -ffast-math in harness -> 1.0f/x emits the IEEE
// div sequence, ~8-10 VALU ops/value; rcp err <=1ulp << u8 quant step).
// VERIFIED WIN round 2: 178.96 -> 159.24 us.
__device__ __forceinline__ float fast_rcp(float x) {
#if __has_builtin(__builtin_amdgcn_rcpf)
    return __builtin_amdgcn_rcpf(x);
#else
    return 1.0f / x;
#endif
}
// async global->LDS, 16B per lane; LDS dest is wave-uniform base + lane*16
__device__ __forceinline__ void gll16(const unsigned short* g, unsigned short* l) {
    __builtin_amdgcn_global_load_lds(
        (const __attribute__((address_space(1))) void*)g,
        (__attribute__((address_space(3))) void*)l, 16, 0, 0);
}

// ---------------------------------------------------------------------------
// prep1: blocks [0,1024): x f32 -> bf16 (2048 elems/block)
//        blocks [1024,1181): W[k][f] -> Wt[f][k] bf16, LDS-tiled
//        blocks [1181,1201): ELL init (all 16 slots = self), cur=1, ovf=0,
//                            + zero task_ctr / bm_done for the fused kernel
// ---------------------------------------------------------------------------
__global__ __launch_bounds__(256) void prep1_kernel(
    const float* __restrict__ x, const float* __restrict__ W,
    unsigned short* __restrict__ xb, unsigned short* __restrict__ wt,
    unsigned short* __restrict__ ell, int* __restrict__ cur,
    int* __restrict__ ovf_cnt, int* __restrict__ task_ctr,
    int* __restrict__ bm_done)
{
    __shared__ float lt[128][33];
    int bid = blockIdx.x, tid = threadIdx.x;
    if (bid < 1024) {
        size_t base = (size_t)bid * 2048 + (size_t)tid * 8;
        const f32x4* p = (const f32x4*)(x + base);
        f32x4 v0 = p[0], v1 = p[1];
        short8 o;
        o[0] = (short)f2bf(v0[0]); o[1] = (short)f2bf(v0[1]);
        o[2] = (short)f2bf(v0[2]); o[3] = (short)f2bf(v0[3]);
        o[4] = (short)f2bf(v1[0]); o[5] = (short)f2bf(v1[1]);
        o[6] = (short)f2bf(v1[2]); o[7] = (short)f2bf(v1[3]);
        *(short8*)(xb + base) = o;
    } else if (bid < 1181) {
        int f0 = (bid - 1024) * 32;
        int f_l = tid & 31, k0 = (tid >> 5) * 16;
        #pragma unroll
        for (int i = 0; i < 16; ++i) {
            int f = f0 + f_l;
            lt[k0 + i][f_l] = (f < FDIM) ? W[(size_t)(k0 + i) * FDIM + f] : 0.f;
        }
        __syncthreads();
        int f_l2 = tid >> 3, ks = (tid & 7) * 16;
        int f = f0 + f_l2;
        if (f < FDIM) {
            short8 o0, o1;
            #pragma unroll
            for (int j = 0; j < 8; ++j) o0[j] = (short)f2bf(lt[ks + j][f_l2]);
            #pragma unroll
            for (int j = 0; j < 8; ++j) o1[j] = (short)f2bf(lt[ks + 8 + j][f_l2]);
            *(short8*)(wt + (size_t)f * 128 + ks)     = o0;
            *(short8*)(wt + (size_t)f * 128 + ks + 8) = o1;
        }
    } else {
        int p = (bid - 1181) * 256 + tid;
        if (p < FDIM) {
            upk8 s;
            #pragma unroll
            for (int j = 0; j < 8; ++j) s[j] = (unsigned short)p;
            *(upk8*)(ell + (size_t)p * ELLW)     = s;
            *(upk8*)(ell + (size_t)p * ELLW + 8) = s;
            cur[p] = 1;
        }
        if (p < NBM) bm_done[p] = 0;
        if (p == FDIM) { *ovf_cnt = 0; *task_ctr = 0; }
    }
}

// ---------------------------------------------------------------------------
// prep2: scatter children into ELL slots 1.. (order irrelevant: max).
// ---------------------------------------------------------------------------
__global__ __launch_bounds__(256) void prep2_kernel(
    const int* __restrict__ epar, const int* __restrict__ echild,
    int* __restrict__ cur, unsigned short* __restrict__ ell,
    int* __restrict__ ovf_cnt, int* __restrict__ ovf_pairs)
{
    int i = blockIdx.x * 256 + threadIdx.x;
    if (i < EDIM) {
        int p = epar[i], c = echild[i];
        if (p != c) {
            int pos = atomicAdd(&cur[p], 1);
            if (pos < ELLW) {
                ell[(size_t)p * ELLW + pos] = (unsigned short)c;
            } else {
                int j = atomicAdd(ovf_cnt, 1);
                if (j < MAXOVF) { ovf_pairs[2 * j] = p; ovf_pairs[2 * j + 1] = c; }
            }
        }
    }
}

// ---------------------------------------------------------------------------
// fused: persistent blocks pull tasks from an atomic queue.
//   task kind 0 = gemm tile (bm,bq): identical math to the verified gemm8i4
//   task kind 1 = segmax slab: identical math to segmax10, restrided for 512T
// Queue order: gemm bm 0..51 first (520 tasks, > 512-block pipeline depth),
// then [10 gemm of bm 52+j | 16 seg slabs of bm j] interleave, then tail
// slabs. Consumers trail their producers by >512 grabs -> producers done.
// Deadlock-free for ANY dispatch order: tasks are pulled by running blocks,
// gemm tasks never wait, and a seg task's producers were all grabbed
// earlier by blocks that run them to completion.
// Cross-XCD visibility: producer __syncthreads (vmcnt drain) + tid0
// __threadfence (agent wbl2) + atomicAdd; consumer spins on device-scope
// RMW. Consumer L1/L2 never cached its probs8 lines this kernel -> no
// stale copies possible.
// ---------------------------------------------------------------------------
__global__ __launch_bounds__(512, 4) void fused_kernel(
    const unsigned short* __restrict__ xb,   // [BDIM][128] bf16
    const unsigned short* __restrict__ wt,   // [FDIM][128] bf16
    const float* __restrict__ bias,
    unsigned char* __restrict__ probs8,      // [BDIM/8][FDIM][8] u8
    const int* __restrict__ cur, const unsigned short* __restrict__ ell,
    const int* __restrict__ ovf_cnt, const int* __restrict__ ovf_pairs,
    float* __restrict__ out,
    int* __restrict__ task_ctr, int* __restrict__ bm_done)
{
    __shared__ unsigned short smem[40000];   // 80000 B: seg table / gemm tiles
    __shared__ int sTask;

    int tid = threadIdx.x;
    int lane = tid & 63, w = tid >> 6;       // 8 waves
    int wm = w >> 2, wn = w & 3;
    int g = lane >> 4, lr = lane & 15;
    int lrow = lane >> 4;                    // row within 4-row chunk
    int lcol = (lane & 15) << 4;             // byte col
    unsigned short* lA = smem;               // 16384 ushorts = 32 KB
    unsigned short* lB = smem + 16384;       // 16384 ushorts = 32 KB

    for (;;) {
        if (tid == 0) sTask = atomicAdd(task_ctr, 1);
        __syncthreads();
        int task = sTask;
        if (task >= NGEMM + NSEG) return;

        int kind, bm = 0, bq = 0, slab = 0;
        if (task < LAGB * 10) {
            kind = 0; bm = task / 10; bq = task % 10;
        } else {
            int r = task - LAGB * 10;
            if (r < (NBM - LAGB) * 26) {
                int grp = r / 26, q = r % 26;
                if (q < 10) { kind = 0; bm = LAGB + grp; bq = q; }
                else        { kind = 1; slab = grp * 16 + (q - 10); }
            } else {
                kind = 1;
                slab = (NBM - LAGB) * 16 + (r - (NBM - LAGB) * 26);
            }
        }

        if (kind == 0) {
            // ---------------- gemm tile (bm, bq) ----------------
            auto stageA = [&]() {
                #pragma unroll
                for (int it = 0; it < 4; ++it) {
                    int ci = w * 4 + it;             // chunk 0..31
                    int row = ci * 4 + lrow;
                    int sw = lcol ^ ((row & 7) << 4);
                    gll16(xb + ((size_t)(bm * 128 + row) << 7) + (sw >> 1),
                          lA + ci * 512);
                }
            };
            auto stageB = [&](int bn) {
                #pragma unroll
                for (int it = 0; it < 4; ++it) {
                    int ci = w * 4 + it;
                    int row = ci * 4 + lrow;
                    int sw = lcol ^ ((row & 7) << 4);
                    gll16(wt + ((size_t)(bn * 128 + row) << 7) + (sw >> 1),
                          lB + ci * 512);
                }
            };
            auto compute = [&](f32x4 (&acc)[4][2]) {
                #pragma unroll
                for (int ks = 0; ks < 4; ++ks) {
                    int cbk = ks * 64 + g * 16;
                    short8 af[4], bf[2];
                    #pragma unroll
                    for (int mi = 0; mi < 4; ++mi) {
                        int row = wm * 64 + mi * 16 + lr;
                        af[mi] = *(const short8*)((const char*)lA + row * 256 + (cbk ^ ((row & 7) << 4)));
                    }
                    #pragma unroll
                    for (int nj = 0; nj < 2; ++nj) {
                        int row = wn * 32 + nj * 16 + lr;
                        bf[nj] = *(const short8*)((const char*)lB + row * 256 + (cbk ^ ((row & 7) << 4)));
                    }
                    #pragma unroll
                    for (int mi = 0; mi < 4; ++mi)
                        #pragma unroll
                        for (int nj = 0; nj < 2; ++nj)
                            acc[mi][nj] = __builtin_amdgcn_mfma_f32_16x16x32_bf16(
                                af[mi], bf[nj], acc[mi][nj], 0, 0, 0);
                }
            };
            auto epilogue = [&](int bn, f32x4 (&acc)[4][2]) {
                #pragma unroll
                for (int nj = 0; nj < 2; ++nj) {
                    int f = bn * 128 + wn * 32 + nj * 16 + lr;
                    bool ok = (f < FDIM);
                    float bb = ok ? bias[f] : 0.f;
                    #pragma unroll
                    for (int mi = 0; mi < 4; ++mi) {
                        unsigned int pk = 0;
                        #pragma unroll
                        for (int j = 0; j < 4; ++j) {
                            float z = acc[mi][nj][j] + bb;
                            float pr = fast_rcp(1.0f + __expf(-z));   // v_rcp_f32
                            unsigned int q = (unsigned int)(pr * 255.f + 0.5f);
                            pk |= q << (8 * j);
                        }
                        if (ok) {
                            int slb = bm * 16 + wm * 8 + mi * 2 + (g >> 1);
                            *(unsigned int*)(probs8 + ((size_t)slb * FDIM + f) * 8 + (g & 1) * 4) = pk;
                        }
                    }
                }
            };

            stageA();
            stageB(bq * 4);
            __syncthreads();                 // drains vmcnt -> tiles resident

            f32x4 zero = {0.f, 0.f, 0.f, 0.f};
            for (int t = 0; t < 4; ++t) {
                f32x4 acc[4][2];
                #pragma unroll
                for (int mi = 0; mi < 4; ++mi) { acc[mi][0] = zero; acc[mi][1] = zero; }
                compute(acc);
                if (t < 3) {
                    __syncthreads();         // all waves done reading lB(t)
                    stageB(bq * 4 + t + 1);  // async B(t+1), hides under epilogue
                    epilogue(bq * 4 + t, acc);
                    __syncthreads();         // drains vmcnt -> lB(t+1) ready
                } else {
                    epilogue(bq * 4 + t, acc);
                }
            }

            __syncthreads();                 // all probs8 stores drained (vmcnt 0)
            if (tid == 0) {
                __threadfence();             // agent-scope: wbl2 -> L3 visible
                atomicAdd(&bm_done[bm], 1);  // device-scope signal
            }
        } else {
            // ---------------- segmax slab ----------------
            int sbm = slab >> 4;
            if (tid == 0) {
                while (atomicAdd(&bm_done[sbm], 0) < NT4)   // coherent RMW poll
                    __builtin_amdgcn_s_sleep(8);
            }
            __syncthreads();
            asm volatile("" ::: "memory");   // no compiler hoist of data loads

            unsigned short* l = smem;        // [FDIM*8] bf16 table
            int b0 = slab * 8;
            const unsigned char* src = probs8 + (size_t)slab * FDIM * 8;

            for (int c = tid; c < FDIM; c += 512) {
                u32x2 v = *(const u32x2*)(src + (size_t)c * 8);
                upk8 o;
                #pragma unroll
                for (int k = 0; k < 4; ++k) {
                    o[k]     = q2bf(v[0], k);
                    o[4 + k] = q2bf(v[1], k);
                }
                *(upk8*)(l + (size_t)c * 8) = o;
            }
            __syncthreads();

            int novf = *ovf_cnt; if (novf > MAXOVF) novf = MAXOVF;

            for (int p0 = tid * 2; p0 < FDIM; p0 += 1024) {
                int p1 = p0 + 1;
                i32x2 dg = *(const i32x2*)(cur + p0);
                upk4 ea = *(const upk4*)(ell + (size_t)p0 * ELLW);
                upk4 eb = *(const upk4*)(ell + (size_t)p1 * ELLW);
                upk8 ma = *(const upk8*)(l + (size_t)ea[0] * 8);
                upk8 mb = *(const upk8*)(l + (size_t)eb[0] * 8);
                ma = umax8(ma, *(const upk8*)(l + (size_t)ea[1] * 8));
                mb = umax8(mb, *(const upk8*)(l + (size_t)eb[1] * 8));
                ma = umax8(ma, *(const upk8*)(l + (size_t)ea[2] * 8));
                mb = umax8(mb, *(const upk8*)(l + (size_t)eb[2] * 8));
                ma = umax8(ma, *(const upk8*)(l + (size_t)ea[3] * 8));
                mb = umax8(mb, *(const upk8*)(l + (size_t)eb[3] * 8));
                if (dg[0] > 4) {
                    upk4 e = *(const upk4*)(ell + (size_t)p0 * ELLW + 4);
                    ma = umax8(ma, *(const upk8*)(l + (size_t)e[0] * 8));
                    ma = umax8(ma, *(const upk8*)(l + (size_t)e[1] * 8));
                    ma = umax8(ma, *(const upk8*)(l + (size_t)e[2] * 8));
                    ma = umax8(ma, *(const upk8*)(l + (size_t)e[3] * 8));
                }
                if (dg[1] > 4) {
                    upk4 e = *(const upk4*)(ell + (size_t)p1 * ELLW + 4);
                    mb = umax8(mb, *(const upk8*)(l + (size_t)e[0] * 8));
                    mb = umax8(mb, *(const upk8*)(l + (size_t)e[1] * 8));
                    mb = umax8(mb, *(const upk8*)(l + (size_t)e[2] * 8));
                    mb = umax8(mb, *(const upk8*)(l + (size_t)e[3] * 8));
                }
                if (dg[0] > 8) {
                    upk8 e = *(const upk8*)(ell + (size_t)p0 * ELLW + 8);
                    #pragma unroll
                    for (int j = 0; j < 8; ++j)
                        ma = umax8(ma, *(const upk8*)(l + (size_t)e[j] * 8));
                }
                if (dg[1] > 8) {
                    upk8 e = *(const upk8*)(ell + (size_t)p1 * ELLW + 8);
                    #pragma unroll
                    for (int j = 0; j < 8; ++j)
                        mb = umax8(mb, *(const upk8*)(l + (size_t)e[j] * 8));
                }
                if (dg[0] > ELLW) {
                    for (int i = 0; i < novf; ++i)
                        if (ovf_pairs[2 * i] == p0)
                            ma = umax8(ma, *(const upk8*)(l + (size_t)ovf_pairs[2 * i + 1] * 8));
                }
                if (dg[1] > ELLW) {
                    for (int i = 0; i < novf; ++i)
                        if (ovf_pairs[2 * i] == p1)
                            mb = umax8(mb, *(const upk8*)(l + (size_t)ovf_pairs[2 * i + 1] * 8));
                }
                size_t o = (size_t)b0 * FDIM + p0;
                #pragma unroll
                for (int r = 0; r < 8; ++r) {
                    f32x2 v2;
                    v2[0] = bf2f(ma[r]) * (1.f / 255.f);
                    v2[1] = bf2f(mb[r]) * (1.f / 255.f);
                    __builtin_nontemporal_store(v2, (f32x2*)(out + o + (size_t)r * FDIM));
                }
            }
        }
        __syncthreads();   // LDS safe to reuse before next task grab
    }
}

// ---------------------------------------------------------------------------
extern "C" void kernel_launch(void* const* d_in, const int* in_sizes, int n_in,
                              void* d_out, int out_size, void* d_ws, size_t ws_size,
                              hipStream_t stream)
{
    const float* x     = (const float*)d_in[0];
    const float* W     = (const float*)d_in[1];
    const float* bias  = (const float*)d_in[2];
    const int*   epar  = (const int*)d_in[3];
    const int*   echild= (const int*)d_in[4];
    float* out = (float*)d_out;

    char* ws = (char*)d_ws;
    size_t off = 0;
    auto alloc = [&](size_t bytes) { size_t o = off; off = (off + bytes + 255) & ~(size_t)255; return o; };
    size_t o_probs  = alloc((size_t)BDIM * FDIM);        // u8 interleaved
    size_t o_xb     = alloc((size_t)BDIM * CDIM * 2);
    size_t o_wt     = alloc((size_t)FDIM * CDIM * 2);
    size_t o_ell    = alloc((size_t)FDIM * ELLW * 2);
    size_t o_cur    = alloc((size_t)FDIM * 4);
    size_t o_ovfc   = alloc(4);
    size_t o_ovfp   = alloc((size_t)MAXOVF * 8);
    size_t o_tc     = alloc(4);
    size_t o_bmd    = alloc((size_t)NBM * 4);
    (void)ws_size; (void)in_sizes; (void)n_in; (void)out_size;

    unsigned char*  probs8 = (unsigned char*)(ws + o_probs);
    unsigned short* xb     = (unsigned short*)(ws + o_xb);
    unsigned short* wt     = (unsigned short*)(ws + o_wt);
    unsigned short* ell    = (unsigned short*)(ws + o_ell);
    int* cur      = (int*)(ws + o_cur);
    int* ovf_cnt  = (int*)(ws + o_ovfc);
    int* ovf_pairs= (int*)(ws + o_ovfp);
    int* task_ctr = (int*)(ws + o_tc);
    int* bm_done  = (int*)(ws + o_bmd);

    prep1_kernel<<<1201, 256, 0, stream>>>(x, W, xb, wt, ell, cur, ovf_cnt,
                                           task_ctr, bm_done);
    prep2_kernel<<<79, 256, 0, stream>>>(epar, echild, cur, ell, ovf_cnt, ovf_pairs);
    fused_kernel<<<512, 512, 0, stream>>>(xb, wt, bias, probs8, cur, ell,
                                          ovf_cnt, ovf_pairs, out,
                                          task_ctr, bm_done);
}

// Round 4
// 153.832 us; speedup vs baseline: 1.4338x; 1.4338x over previous
//
#include <hip/hip_runtime.h>
#include <hip/hip_bf16.h>

#define BDIM 16384
#define CDIM 128
#define FDIM 5000
#define EDIM 20000
#define ELLW 16
#define MAXOVF 20000
#define NT4  10       // n-tile QUADS: 40 n-tiles / 4

typedef __attribute__((ext_vector_type(8))) short short8;
typedef __attribute__((ext_vector_type(4))) float f32x4;
typedef __attribute__((ext_vector_type(2))) float f32x2;
typedef __attribute__((ext_vector_type(2))) int i32x2;
typedef __attribute__((ext_vector_type(8))) unsigned short upk8;
typedef __attribute__((ext_vector_type(4))) unsigned short upk4;
typedef __attribute__((ext_vector_type(2))) unsigned int u32x2;

__device__ __forceinline__ unsigned short f2bf(float f) {
    unsigned int u = __builtin_bit_cast(unsigned int, f);
    u = (u + 0x7fffu + ((u >> 16) & 1u)) >> 16;   // RNE
    return (unsigned short)u;
}
__device__ __forceinline__ float bf2f(unsigned short s) {
    unsigned int u = ((unsigned int)s) << 16;
    return __builtin_bit_cast(float, u);
}
__device__ __forceinline__ upk8 umax8(upk8 a, upk8 b) {
#if __has_builtin(__builtin_elementwise_max)
    return __builtin_elementwise_max(a, b);   // 4x v_pk_max_u16
#else
    upk8 r;
    #pragma unroll
    for (int j = 0; j < 8; ++j) r[j] = a[j] > b[j] ? a[j] : b[j];
    return r;
#endif
}
// single v_rcp_f32 (no -ffast-math in harness -> 1.0f/x emits the IEEE
// div sequence). VERIFIED WIN round 2: 178.96 -> 159.24 us.
__device__ __forceinline__ float fast_rcp(float x) {
#if __has_builtin(__builtin_amdgcn_rcpf)
    return __builtin_amdgcn_rcpf(x);
#else
    return 1.0f / x;
#endif
}
// order-preserving u16 key of a bf16 pattern h (per 16-bit half, packed u32):
// pos: k = h | 0x8000 ; neg: k = ~h  -> unsigned order == float order
__device__ __forceinline__ unsigned int key2(unsigned int h) {
    unsigned int t = (h >> 15) & 0x00010001u;
    return h ^ (t * 0x7FFFu + 0x80008000u);
}
// inverse: k -> bf16 bits
__device__ __forceinline__ unsigned short unkey(unsigned short k) {
    unsigned int s = (k >> 15) & 1u;
    return (unsigned short)(k ^ (0x8000u + ((s ^ 1u) * 0x7FFFu)));
}
// async global->LDS, 16B per lane; LDS dest = readfirstlane(base) + lane*16
__device__ __forceinline__ void gll16(const unsigned short* g, unsigned short* l) {
    __builtin_amdgcn_global_load_lds(
        (const __attribute__((address_space(1))) void*)g,
        (__attribute__((address_space(3))) void*)l, 16, 0, 0);
}

// ---------------------------------------------------------------------------
// prep1: blocks [0,1024): x f32 -> bf16 (2048 elems/block)
//        blocks [1024,1181): W[k][f] -> Wt[f][k] bf16, LDS-tiled
//        blocks [1181,1201): ELL init (all 16 slots = self), cur=1, ovf=0
// ---------------------------------------------------------------------------
__global__ __launch_bounds__(256) void prep1_kernel(
    const float* __restrict__ x, const float* __restrict__ W,
    unsigned short* __restrict__ xb, unsigned short* __restrict__ wt,
    unsigned short* __restrict__ ell, int* __restrict__ cur,
    int* __restrict__ ovf_cnt)
{
    __shared__ float lt[128][33];
    int bid = blockIdx.x, tid = threadIdx.x;
    if (bid < 1024) {
        size_t base = (size_t)bid * 2048 + (size_t)tid * 8;
        const f32x4* p = (const f32x4*)(x + base);
        f32x4 v0 = p[0], v1 = p[1];
        short8 o;
        o[0] = (short)f2bf(v0[0]); o[1] = (short)f2bf(v0[1]);
        o[2] = (short)f2bf(v0[2]); o[3] = (short)f2bf(v0[3]);
        o[4] = (short)f2bf(v1[0]); o[5] = (short)f2bf(v1[1]);
        o[6] = (short)f2bf(v1[2]); o[7] = (short)f2bf(v1[3]);
        *(short8*)(xb + base) = o;
    } else if (bid < 1181) {
        int f0 = (bid - 1024) * 32;
        int f_l = tid & 31, k0 = (tid >> 5) * 16;
        #pragma unroll
        for (int i = 0; i < 16; ++i) {
            int f = f0 + f_l;
            lt[k0 + i][f_l] = (f < FDIM) ? W[(size_t)(k0 + i) * FDIM + f] : 0.f;
        }
        __syncthreads();
        int f_l2 = tid >> 3, ks = (tid & 7) * 16;
        int f = f0 + f_l2;
        if (f < FDIM) {
            short8 o0, o1;
            #pragma unroll
            for (int j = 0; j < 8; ++j) o0[j] = (short)f2bf(lt[ks + j][f_l2]);
            #pragma unroll
            for (int j = 0; j < 8; ++j) o1[j] = (short)f2bf(lt[ks + 8 + j][f_l2]);
            *(short8*)(wt + (size_t)f * 128 + ks)     = o0;
            *(short8*)(wt + (size_t)f * 128 + ks + 8) = o1;
        }
    } else {
        int p = (bid - 1181) * 256 + tid;
        if (p < FDIM) {
            upk8 s;
            #pragma unroll
            for (int j = 0; j < 8; ++j) s[j] = (unsigned short)p;
            *(upk8*)(ell + (size_t)p * ELLW)     = s;
            *(upk8*)(ell + (size_t)p * ELLW + 8) = s;
            cur[p] = 1;
        }
        if (p == FDIM) *ovf_cnt = 0;
    }
}

// ---------------------------------------------------------------------------
// prep2: scatter children into ELL slots 1.. (order irrelevant: max).
// ---------------------------------------------------------------------------
__global__ __launch_bounds__(256) void prep2_kernel(
    const int* __restrict__ epar, const int* __restrict__ echild,
    int* __restrict__ cur, unsigned short* __restrict__ ell,
    int* __restrict__ ovf_cnt, int* __restrict__ ovf_pairs)
{
    int i = blockIdx.x * 256 + threadIdx.x;
    if (i < EDIM) {
        int p = epar[i], c = echild[i];
        if (p != c) {
            int pos = atomicAdd(&cur[p], 1);
            if (pos < ELLW) {
                ell[(size_t)p * ELLW + pos] = (unsigned short)c;
            } else {
                int j = atomicAdd(ovf_cnt, 1);
                if (j < MAXOVF) { ovf_pairs[2 * j] = p; ovf_pairs[2 * j + 1] = c; }
            }
        }
    }
}

// ---------------------------------------------------------------------------
// gemm8k: identical structure to the verified gemm8i4 (159.24 us pipeline);
// epilogue stores ORDER-KEYED bf16 logits (z = acc + bias) instead of
// sigmoid-quantized u8. sigmoid is monotone -> max commutes -> it moves to
// segmax's output (hidden under write BW). Removes both transcendentals
// + quant chain from gemm's critical path (~13 us chip-wide VALU).
// probs16 layout: [BDIM/8][FDIM][8] u16 keys.
// ---------------------------------------------------------------------------
__global__ __launch_bounds__(512, 4) void gemm8k_kernel(
    const unsigned short* __restrict__ xb,   // [BDIM][128] bf16
    const unsigned short* __restrict__ wt,   // [FDIM][128] bf16
    const float* __restrict__ bias,
    unsigned short* __restrict__ probs16)    // [BDIM/8][FDIM][8] u16 keys
{
    __shared__ unsigned short lA[128 * 128];
    __shared__ unsigned short lB[128 * 128];

    int bid0 = blockIdx.x;
    int bid  = (bid0 & 7) * (128 * NT4 / 8) + (bid0 >> 3);   // XCD swizzle
    int bm = bid / NT4, bq = bid % NT4;
    int tid = threadIdx.x;
    int lane = tid & 63, w = tid >> 6;       // 8 waves
    int wm = w >> 2, wn = w & 3;
    int g = lane >> 4, lr = lane & 15;
    int lrow = lane >> 4;                    // row within 4-row chunk
    int lcol = (lane & 15) << 4;             // byte col

    auto stageA = [&]() {
        #pragma unroll
        for (int it = 0; it < 4; ++it) {
            int ci = w * 4 + it;             // chunk 0..31
            int row = ci * 4 + lrow;
            int sw = lcol ^ ((row & 7) << 4);
            gll16(xb + ((size_t)(bm * 128 + row) << 7) + (sw >> 1),
                  lA + ci * 512);
        }
    };
    auto stageB = [&](int bn) {
        #pragma unroll
        for (int it = 0; it < 4; ++it) {
            int ci = w * 4 + it;
            int row = ci * 4 + lrow;
            int sw = lcol ^ ((row & 7) << 4);
            gll16(wt + ((size_t)(bn * 128 + row) << 7) + (sw >> 1),
                  lB + ci * 512);
        }
    };
    auto compute = [&](f32x4 (&acc)[4][2]) {
        #pragma unroll
        for (int ks = 0; ks < 4; ++ks) {
            int cbk = ks * 64 + g * 16;
            short8 af[4], bf[2];
            #pragma unroll
            for (int mi = 0; mi < 4; ++mi) {
                int row = wm * 64 + mi * 16 + lr;
                af[mi] = *(const short8*)((const char*)lA + row * 256 + (cbk ^ ((row & 7) << 4)));
            }
            #pragma unroll
            for (int nj = 0; nj < 2; ++nj) {
                int row = wn * 32 + nj * 16 + lr;
                bf[nj] = *(const short8*)((const char*)lB + row * 256 + (cbk ^ ((row & 7) << 4)));
            }
            #pragma unroll
            for (int mi = 0; mi < 4; ++mi)
                #pragma unroll
                for (int nj = 0; nj < 2; ++nj)
                    acc[mi][nj] = __builtin_amdgcn_mfma_f32_16x16x32_bf16(
                        af[mi], bf[nj], acc[mi][nj], 0, 0, 0);
        }
    };
    auto epilogue = [&](int bn, f32x4 (&acc)[4][2]) {
        #pragma unroll
        for (int nj = 0; nj < 2; ++nj) {
            int f = bn * 128 + wn * 32 + nj * 16 + lr;
            bool ok = (f < FDIM);
            float bb = ok ? bias[f] : 0.f;
            #pragma unroll
            for (int mi = 0; mi < 4; ++mi) {
                float z0 = acc[mi][nj][0] + bb;
                float z1 = acc[mi][nj][1] + bb;
                float z2 = acc[mi][nj][2] + bb;
                float z3 = acc[mi][nj][3] + bb;
                unsigned int h01, h23;   // packed bf16 (low = first operand)
                asm("v_cvt_pk_bf16_f32 %0, %1, %2" : "=v"(h01) : "v"(z0), "v"(z1));
                asm("v_cvt_pk_bf16_f32 %0, %1, %2" : "=v"(h23) : "v"(z2), "v"(z3));
                u32x2 st;
                st[0] = key2(h01);
                st[1] = key2(h23);
                if (ok) {
                    int slab = bm * 16 + wm * 8 + mi * 2 + (g >> 1);
                    *(u32x2*)(probs16 + ((size_t)slab * FDIM + f) * 8 + (g & 1) * 4) = st;
                }
            }
        }
    };

    stageA();
    stageB(bq * 4);
    __syncthreads();                     // drains vmcnt -> tiles resident

    f32x4 zero = {0.f, 0.f, 0.f, 0.f};
    for (int t = 0; t < 4; ++t) {
        f32x4 acc[4][2];
        #pragma unroll
        for (int mi = 0; mi < 4; ++mi) { acc[mi][0] = zero; acc[mi][1] = zero; }
        compute(acc);
        if (t < 3) {
            __syncthreads();             // all waves done reading lB(t)
            stageB(bq * 4 + t + 1);      // async B(t+1), hides under epilogue
            epilogue(bq * 4 + t, acc);
            __syncthreads();             // drains vmcnt -> lB(t+1) ready
        } else {
            epilogue(bq * 4 + t, acc);
        }
    }
}

// ---------------------------------------------------------------------------
// segmax12: table staging is now pure global_load_lds (u16 keys verbatim,
// no conversion VALU). Max chains unchanged (u16 keys are unsigned-order-
// correct). Final store: unkey -> bf16 -> sigmoid (hidden under write BW).
// ---------------------------------------------------------------------------
__global__ __launch_bounds__(1024) void segmax12_kernel(
    const unsigned short* __restrict__ probs16,
    const int* __restrict__ cur, const unsigned short* __restrict__ ell,
    const int* __restrict__ ovf_cnt, const int* __restrict__ ovf_pairs,
    float* __restrict__ out)
{
    __shared__ unsigned short l[FDIM * 8];   // 80000 B of u16 keys
    int slab = blockIdx.x;
    int b0 = slab * 8;
    int tid = threadIdx.x;
    const unsigned short* src = probs16 + (size_t)slab * FDIM * 8;

    for (int c = tid; c < FDIM; c += 1024) {
        // 16 B per term: direct async copy; lane layout matches (c = base+lane)
        gll16(src + (size_t)c * 8, l + (size_t)c * 8);
    }
    __syncthreads();                         // drains vmcnt -> table resident

    int novf = *ovf_cnt; if (novf > MAXOVF) novf = MAXOVF;

    for (int p0 = tid * 2; p0 < FDIM; p0 += 2048) {
        int p1 = p0 + 1;
        i32x2 dg = *(const i32x2*)(cur + p0);
        upk4 ea = *(const upk4*)(ell + (size_t)p0 * ELLW);
        upk4 eb = *(const upk4*)(ell + (size_t)p1 * ELLW);
        upk8 ma = *(const upk8*)(l + (size_t)ea[0] * 8);
        upk8 mb = *(const upk8*)(l + (size_t)eb[0] * 8);
        ma = umax8(ma, *(const upk8*)(l + (size_t)ea[1] * 8));
        mb = umax8(mb, *(const upk8*)(l + (size_t)eb[1] * 8));
        ma = umax8(ma, *(const upk8*)(l + (size_t)ea[2] * 8));
        mb = umax8(mb, *(const upk8*)(l + (size_t)eb[2] * 8));
        ma = umax8(ma, *(const upk8*)(l + (size_t)ea[3] * 8));
        mb = umax8(mb, *(const upk8*)(l + (size_t)eb[3] * 8));
        if (dg[0] > 4) {
            upk4 e = *(const upk4*)(ell + (size_t)p0 * ELLW + 4);
            ma = umax8(ma, *(const upk8*)(l + (size_t)e[0] * 8));
            ma = umax8(ma, *(const upk8*)(l + (size_t)e[1] * 8));
            ma = umax8(ma, *(const upk8*)(l + (size_t)e[2] * 8));
            ma = umax8(ma, *(const upk8*)(l + (size_t)e[3] * 8));
        }
        if (dg[1] > 4) {
            upk4 e = *(const upk4*)(ell + (size_t)p1 * ELLW + 4);
            mb = umax8(mb, *(const upk8*)(l + (size_t)e[0] * 8));
            mb = umax8(mb, *(const upk8*)(l + (size_t)e[1] * 8));
            mb = umax8(mb, *(const upk8*)(l + (size_t)e[2] * 8));
            mb = umax8(mb, *(const upk8*)(l + (size_t)e[3] * 8));
        }
        if (dg[0] > 8) {
            upk8 e = *(const upk8*)(ell + (size_t)p0 * ELLW + 8);
            #pragma unroll
            for (int j = 0; j < 8; ++j)
                ma = umax8(ma, *(const upk8*)(l + (size_t)e[j] * 8));
        }
        if (dg[1] > 8) {
            upk8 e = *(const upk8*)(ell + (size_t)p1 * ELLW + 8);
            #pragma unroll
            for (int j = 0; j < 8; ++j)
                mb = umax8(mb, *(const upk8*)(l + (size_t)e[j] * 8));
        }
        if (dg[0] > ELLW) {
            for (int i = 0; i < novf; ++i)
                if (ovf_pairs[2 * i] == p0)
                    ma = umax8(ma, *(const upk8*)(l + (size_t)ovf_pairs[2 * i + 1] * 8));
        }
        if (dg[1] > ELLW) {
            for (int i = 0; i < novf; ++i)
                if (ovf_pairs[2 * i] == p1)
                    mb = umax8(mb, *(const upk8*)(l + (size_t)ovf_pairs[2 * i + 1] * 8));
        }
        size_t o = (size_t)b0 * FDIM + p0;
        #pragma unroll
        for (int r = 0; r < 8; ++r) {
            float za = bf2f(unkey(ma[r]));
            float zb = bf2f(unkey(mb[r]));
            f32x2 v2;
            v2[0] = fast_rcp(1.0f + __expf(-za));
            v2[1] = fast_rcp(1.0f + __expf(-zb));
            __builtin_nontemporal_store(v2, (f32x2*)(out + o + (size_t)r * FDIM));
        }
    }
}

// ---------------------------------------------------------------------------
extern "C" void kernel_launch(void* const* d_in, const int* in_sizes, int n_in,
                              void* d_out, int out_size, void* d_ws, size_t ws_size,
                              hipStream_t stream)
{
    const float* x     = (const float*)d_in[0];
    const float* W     = (const float*)d_in[1];
    const float* bias  = (const float*)d_in[2];
    const int*   epar  = (const int*)d_in[3];
    const int*   echild= (const int*)d_in[4];
    float* out = (float*)d_out;

    char* ws = (char*)d_ws;
    size_t off = 0;
    auto alloc = [&](size_t bytes) { size_t o = off; off = (off + bytes + 255) & ~(size_t)255; return o; };
    size_t o_probs  = alloc((size_t)BDIM * FDIM * 2);    // u16 keys
    size_t o_xb     = alloc((size_t)BDIM * CDIM * 2);
    size_t o_wt     = alloc((size_t)FDIM * CDIM * 2);
    size_t o_ell    = alloc((size_t)FDIM * ELLW * 2);
    size_t o_cur    = alloc((size_t)FDIM * 4);
    size_t o_ovfc   = alloc(4);
    size_t o_ovfp   = alloc((size_t)MAXOVF * 8);
    (void)ws_size; (void)in_sizes; (void)n_in; (void)out_size;

    unsigned short* probs16 = (unsigned short*)(ws + o_probs);
    unsigned short* xb      = (unsigned short*)(ws + o_xb);
    unsigned short* wt      = (unsigned short*)(ws + o_wt);
    unsigned short* ell     = (unsigned short*)(ws + o_ell);
    int* cur      = (int*)(ws + o_cur);
    int* ovf_cnt  = (int*)(ws + o_ovfc);
    int* ovf_pairs= (int*)(ws + o_ovfp);

    prep1_kernel<<<1201, 256, 0, stream>>>(x, W, xb, wt, ell, cur, ovf_cnt);
    prep2_kernel<<<79, 256, 0, stream>>>(epar, echild, cur, ell, ovf_cnt, ovf_pairs);
    gemm8k_kernel<<<128 * NT4, 512, 0, stream>>>(xb, wt, bias, probs16);
    segmax12_kernel<<<BDIM / 8, 1024, 0, stream>>>(probs16, cur, ell,
                                                   ovf_cnt, ovf_pairs, out);
}